// Round 12
// baseline (489.849 us; speedup 1.0000x reference)
//
#include <hip/hip_runtime.h>
#include <hip/hip_bf16.h>
#include <math.h>

#define B_ 2048
#define N_ 512
#define D_ 128
#define H_ 256
#define BANDf 2e-4f     // repair band: >= 2x worst-case bf16x3 score error (~1e-5..5e-5)
#define TILE_R 32
#define GRID_MLP 768    // 3 blocks/CU

typedef __attribute__((ext_vector_type(8))) short bf16x8;
typedef __attribute__((ext_vector_type(4))) float f32x4;

__device__ __forceinline__ short f2bf(float x) {          // rne f32 -> bf16
    unsigned u = __float_as_uint(x);
    u = u + 0x7fffu + ((u >> 16) & 1u);
    return (short)(u >> 16);
}
__device__ __forceinline__ float bf2f(short h) {
    return __uint_as_float(((unsigned)(unsigned short)h) << 16);
}
__device__ __forceinline__ unsigned cvt_pk_bf16(float a, float b) { // [lo]=bf(a) [hi]=bf(b)
    unsigned r;
    asm("v_cvt_pk_bf16_f32 %0, %1, %2" : "=v"(r) : "v"(a), "v"(b));
    return r;
}
template<int K>
__device__ __forceinline__ float dpp_shr_add(float zz) {   // row_shr add within 16-lane rows
    int s = __builtin_amdgcn_update_dpp(0, __float_as_int(zz), 0x110 | K, 0xf, 0xf, true);
    return zz + __int_as_float(s);
}
__device__ __forceinline__ void gld_lds16(const float* g, float* l) {
    __builtin_amdgcn_global_load_lds(
        (const __attribute__((address_space(1))) void*)g,
        (__attribute__((address_space(3))) void*)l, 16, 0, 0);
}

// ---------------- W1 pre-pack: fragment-ordered bf16 hi/lo ----------------
// B-frag (16x16x32): lane l holds B[k = ks*32 + (l>>4)*8 + j][n = nf*16 + (l&15)]
__global__ __launch_bounds__(256) void pack_w(const float* __restrict__ W1,
                                              short* __restrict__ WpH,
                                              short* __restrict__ WpL)
{
    int tid = blockIdx.x * 256 + threadIdx.x;   // 0..4095
    int l  = tid & 63;
    int ks = (tid >> 6) & 3;
    int nf = tid >> 8;
    int n  = nf * 16 + (l & 15);
    int kb = ks * 32 + ((l >> 4) << 3);
    bf16x8 hi, lo;
    #pragma unroll
    for (int j = 0; j < 8; ++j) {
        float w = W1[(size_t)(kb + j) * H_ + n];
        short h = f2bf(w);
        hi[j] = h;
        lo[j] = f2bf(w - bf2f(h));
    }
    *(bf16x8*)&WpH[(size_t)tid * 8] = hi;
    *(bf16x8*)&WpL[(size_t)tid * 8] = lo;
}

// ---------------- MLP: 2-phase global_load_lds pipeline, f32 LDS dbuf, cvt-at-read ----------------
// 768 blocks x 256 thr (4 waves), grid-stride over 32768 tiles of 32 rows x 256 cols.
// Wave wn owns cols wn*64..+63 (q=0..3), rows 0..31 (mf=0..1). acc 32, B-hi 64 VGPR.
__global__ __launch_bounds__(256, 3) void mlp_mfma(
    const float* __restrict__ X, const short* __restrict__ WpH,
    const short* __restrict__ WpL, const float* __restrict__ b1,
    const float* __restrict__ W2, const float* __restrict__ b2,
    float* __restrict__ ls)
{
    __shared__ float Xf[2][TILE_R * 128];   // swizzled f32 tiles (16 KB each)
    __shared__ float zl[2][128];            // per-wave z partials (4 col-groups x 32 rows)

    const int t    = threadIdx.x;
    const int lane = t & 63;
    const int wn   = t >> 6;

    const bf16x8* WH = (const bf16x8*)WpH;
    const bf16x8* WL = (const bf16x8*)WpL;

    // B-hi resident (64 VGPR); B-lo streamed from L2 per ks
    bf16x8 Bhi[4][4];
    #pragma unroll
    for (int q = 0; q < 4; ++q)
        #pragma unroll
        for (int ks = 0; ks < 4; ++ks)
            Bhi[q][ks] = WH[((wn * 4 + q) * 4 + ks) * 64 + lane];

    float b1v[4], w2v[4];
    #pragma unroll
    for (int q = 0; q < 4; ++q) {
        int c = wn * 64 + q * 16 + (lane & 15);
        b1v[q] = b1[c];
        w2v[q] = W2[c];
    }
    const float b2v = b2[0];

    const int NTILES = (B_ * N_) / TILE_R;  // 32768

    // stage tile tt into LDS buffer nb: 4 global_load_lds_dwordx4 per wave, pre-swizzled source
    auto stage = [&](int tt, int nb) {
        const float* src = X + (size_t)tt * TILE_R * 128;
        #pragma unroll
        for (int j = 0; j < 4; ++j) {
            int g = wn * 4 + j;                       // 2-row group 0..15 (wave-uniform)
            int r = g * 2 + (lane >> 5);              // row 0..31
            int c = (lane & 31) ^ (r & 7);            // inverse-swizzled 16B chunk
            gld_lds16(src + r * 128 + c * 4, &Xf[nb][g * 256]);
        }
    };

    // prologue: stage first tile into buf 0
    int tile = blockIdx.x;
    if (tile < NTILES) stage(tile, 0);
    __syncthreads();

    int it = 0;
    size_t m_prev = 0;

    for (; tile < NTILES; tile += GRID_MLP, ++it) {
        const int cur = it & 1, nxt = cur ^ 1;

        // (1) issue next tile's DMA first — lands during this tile's MFMA phase
        if (tile + GRID_MLP < NTILES) stage(tile + GRID_MLP, nxt);
        __builtin_amdgcn_sched_barrier(0);

        // (2) deferred epilogue of previous tile (reads zl[nxt], barrier-protected)
        if (it > 0 && t < TILE_R) {
            float z = zl[nxt][t] + zl[nxt][32 + t] + zl[nxt][64 + t] + zl[nxt][96 + t] + b2v;
            ls[m_prev + t] = 1.f / (1.f + expf(-z)) - 0.5f;
        }

        // (3) MFMA on buf cur, converting f32->bf16 hi/lo at fragment read
        f32x4 acc[2][4];
        #pragma unroll
        for (int mf = 0; mf < 2; ++mf)
            #pragma unroll
            for (int q = 0; q < 4; ++q)
                acc[mf][q] = (f32x4){0.f, 0.f, 0.f, 0.f};

        #pragma unroll
        for (int ks = 0; ks < 4; ++ks) {
            bf16x8 Blo[4];
            #pragma unroll
            for (int q = 0; q < 4; ++q)
                Blo[q] = WL[((wn * 4 + q) * 4 + ks) * 64 + lane];
            #pragma unroll
            for (int mf = 0; mf < 2; ++mf) {
                int r  = mf * 16 + (lane & 15);
                int k0 = ks * 32 + ((lane >> 4) << 3);
                int sw = (r & 7) << 2;
                f32x4 v0 = *(const f32x4*)&Xf[cur][r * 128 + (k0 ^ sw)];
                f32x4 v1 = *(const f32x4*)&Xf[cur][r * 128 + ((k0 + 4) ^ sw)];
                union { unsigned u[4]; bf16x8 v; } Ah, Al;
                Ah.u[0] = cvt_pk_bf16(v0[0], v0[1]);
                Ah.u[1] = cvt_pk_bf16(v0[2], v0[3]);
                Ah.u[2] = cvt_pk_bf16(v1[0], v1[1]);
                Ah.u[3] = cvt_pk_bf16(v1[2], v1[3]);
                float l0 = v0[0] - __uint_as_float(Ah.u[0] << 16);
                float l1 = v0[1] - __uint_as_float(Ah.u[0] & 0xffff0000u);
                float l2 = v0[2] - __uint_as_float(Ah.u[1] << 16);
                float l3 = v0[3] - __uint_as_float(Ah.u[1] & 0xffff0000u);
                float l4 = v1[0] - __uint_as_float(Ah.u[2] << 16);
                float l5 = v1[1] - __uint_as_float(Ah.u[2] & 0xffff0000u);
                float l6 = v1[2] - __uint_as_float(Ah.u[3] << 16);
                float l7 = v1[3] - __uint_as_float(Ah.u[3] & 0xffff0000u);
                Al.u[0] = cvt_pk_bf16(l0, l1);
                Al.u[1] = cvt_pk_bf16(l2, l3);
                Al.u[2] = cvt_pk_bf16(l4, l5);
                Al.u[3] = cvt_pk_bf16(l6, l7);
                #pragma unroll
                for (int q = 0; q < 4; ++q) {
                    acc[mf][q] = __builtin_amdgcn_mfma_f32_16x16x32_bf16(Ah.v, Bhi[q][ks], acc[mf][q], 0, 0, 0);
                    acc[mf][q] = __builtin_amdgcn_mfma_f32_16x16x32_bf16(Al.v, Bhi[q][ks], acc[mf][q], 0, 0, 0);
                    acc[mf][q] = __builtin_amdgcn_mfma_f32_16x16x32_bf16(Ah.v, Blo[q],     acc[mf][q], 0, 0, 0);
                }
            }
        }

        // (4) z partials -> zl[cur] via DPP row-reduce (VALU pipe)
        #pragma unroll
        for (int mf = 0; mf < 2; ++mf) {
            #pragma unroll
            for (int i = 0; i < 4; ++i) {
                float zz = 0.f;
                #pragma unroll
                for (int q = 0; q < 4; ++q) {
                    float h = acc[mf][q][i] + b1v[q];
                    h = h > 0.f ? h : 0.f;
                    zz += h * w2v[q];
                }
                zz = dpp_shr_add<1>(zz);
                zz = dpp_shr_add<2>(zz);
                zz = dpp_shr_add<4>(zz);
                zz = dpp_shr_add<8>(zz);        // lane (l&15)==15 holds row sum over wave's 64 cols
                if ((lane & 15) == 15)
                    zl[cur][wn * 32 + mf * 16 + ((lane >> 4) << 2) + i] = zz;
            }
        }

        m_prev = (size_t)tile * TILE_R;

        // (5) single barrier per tile: drains the DMA issued in (1) after a full MFMA phase
        __syncthreads();
    }

    if (it > 0 && t < TILE_R) {                 // final deferred epilogue
        const int lastb = (it - 1) & 1;
        float z = zl[lastb][t] + zl[lastb][32 + t] + zl[lastb][64 + t] + zl[lastb][96 + t] + b2v;
        ls[m_prev + t] = 1.f / (1.f + expf(-z)) - 0.5f;
    }
}

// ---------------- radix-select machinery (ballot-based, no DS ops) ----------------
__device__ __forceinline__ unsigned f2key(float f) {      // monotone float->uint
    unsigned u = __float_as_uint(f);
    return (u & 0x80000000u) ? ~u : (u | 0x80000000u);
}
__device__ __forceinline__ float key2f(unsigned k) {
    return __uint_as_float((k & 0x80000000u) ? (k & 0x7fffffffu) : ~k);
}
__device__ __forceinline__ int lane_lt_count(unsigned long long m) {
    return __builtin_amdgcn_mbcnt_hi((unsigned)(m >> 32),
           __builtin_amdgcn_mbcnt_lo((unsigned)m, 0));
}

__device__ __forceinline__ void radix_topk(const unsigned (&key)[8], int k,
                                           unsigned &T, int &need)
{
    unsigned prefix = 0, maskhi = 0;
    int kk = k;
    for (int bit = 31; bit >= 0; --bit) {
        unsigned b = 1u << bit;
        int cnt1 = 0;
        #pragma unroll
        for (int j = 0; j < 8; ++j) {
            bool one = ((key[j] & maskhi) == prefix) && (key[j] & b);
            cnt1 += __popcll(__ballot(one));
        }
        if (cnt1 >= kk) prefix |= b; else kk -= cnt1;
        maskhi |= b;
    }
    T = prefix; need = kk;
}

// membership, lowest-global-index tiebreak (slot n = l + 64*j => rank by (j, lane))
__device__ __forceinline__ void tie_member(const unsigned (&key)[8], unsigned T,
                                           int need, bool (&mem)[8])
{
    int base = 0;
    #pragma unroll
    for (int j = 0; j < 8; ++j) {
        unsigned long long eb = __ballot(key[j] == T);
        int r = base + lane_lt_count(eb);
        mem[j] = (key[j] > T) || ((key[j] == T) && (r < need));
        base += __popcll(eb);
    }
}

// ---------------- selection: 1 wave/row, barrier-free; exact band-repair ----------------
__global__ __launch_bounds__(256) void select_kernel(
    const float* __restrict__ ls, const float* __restrict__ spread,
    const float* __restrict__ vol, const float* __restrict__ X,
    const float* __restrict__ W1, const float* __restrict__ b1,
    const float* __restrict__ W2, const float* __restrict__ b2,
    float* __restrict__ action, float* __restrict__ conf_out)
{
    const int t = threadIdx.x;
    const int l = t & 63;
    const int w = t >> 6;
    const int b = blockIdx.x * 4 + w;
    const size_t base = (size_t)b * N_;

    float rv[8], lsv[8];
    unsigned kr[8];
    bool anyv = false;
    #pragma unroll
    for (int j = 0; j < 8; ++j) {
        int n = l + (j << 6);
        float sp = spread[base + n];
        float vo = vol[base + n];
        bool valid = isfinite(sp) && (sp > 0.f);
        rv[j]  = valid ? (vo / (sp + 1e-8f)) : -INFINITY;
        lsv[j] = ls[base + n];
        anyv |= valid;
        kr[j] = f2key(rv[j]);
    }
    bool allow_all = (__any((int)anyv) == 0);

    unsigned T50; int need50;
    radix_topk(kr, 50, T50, need50);
    bool mem50[8];
    tie_member(kr, T50, need50, mem50);

    float mabs[8];
    unsigned km[8];
    #pragma unroll
    for (int j = 0; j < 8; ++j) {
        bool u = allow_all || mem50[j];
        mabs[j] = u ? fabsf(lsv[j]) : -INFINITY;
        km[j] = f2key(mabs[j]);
    }
    unsigned T10; int need10;
    radix_topk(km, 10, T10, need10);
    bool mem10[8];
    tie_member(km, T10, need10, mem10);
    float b10 = key2f(T10);

    // Z, conf in one butterfly
    float zp = 0.f, cf = -INFINITY;
    #pragma unroll
    for (int j = 0; j < 8; ++j) {
        if (mem10[j]) zp += mabs[j];
        cf = fmaxf(cf, mabs[j]);
    }
    #pragma unroll
    for (int s = 1; s < 64; s <<= 1) {
        zp += __shfl_xor(zp, s, 64);
        cf = fmaxf(cf, __shfl_xor(cf, s, 64));
    }
    float conf = cf;

    // band analysis
    bool confclose = fabsf(conf - 0.05f) <= BANDf;
    bool inband[8];
    int nb = 0;
    #pragma unroll
    for (int j = 0; j < 8; ++j) {
        inband[j] = (mabs[j] != -INFINITY) && (fabsf(mabs[j] - b10) <= BANDf);
        nb += __popcll(__ballot(inband[j]));
    }
    bool redo = (nb >= 2) || confclose;

    if (!redo) {
        float cfin  = isfinite(conf) ? conf : 0.f;
        float scale = (cfin >= 0.05f) ? (1.f / (zp + 1e-8f)) : 0.f;
        #pragma unroll
        for (int j = 0; j < 8; ++j) {
            int n = l + (j << 6);
            action[base + n] = mem10[j] ? lsv[j] * scale : 0.f;
        }
        if (l == 0) conf_out[b] = cfin;
        return;
    }

    // ---- exact recompute of band/conf candidates (wave-cooperative) ----
    const float2* xr2 = (const float2*)&X[base * D_];   // row view: [N][64 float2]
    float4 bb = *(const float4*)&b1[l * 4];
    float4 ww = *(const float4*)&W2[l * 4];
    const float b2v = b2[0];

    #pragma unroll
    for (int j = 0; j < 8; ++j) {
        bool cand = (nb >= 2 && inband[j]) || (confclose && mabs[j] == conf);
        unsigned long long bal = __ballot(cand);
        while (bal) {
            int s = __ffsll((long long)bal) - 1;
            bal &= bal - 1;
            int asset = s + (j << 6);
            float2 x2 = xr2[(size_t)asset * 64 + l];    // lane l holds k=2l,2l+1
            float h0 = 0.f, h1 = 0.f, h2 = 0.f, h3 = 0.f;
            #pragma unroll 16
            for (int kk = 0; kk < D_; ++kk) {
                float xk = __shfl((kk & 1) ? x2.y : x2.x, kk >> 1, 64);
                float4 wv = *(const float4*)&W1[(size_t)kk * H_ + l * 4];
                h0 += xk * wv.x; h1 += xk * wv.y; h2 += xk * wv.z; h3 += xk * wv.w;
            }
            h0 += bb.x; h1 += bb.y; h2 += bb.z; h3 += bb.w;
            float zz = (h0 > 0.f ? h0 : 0.f) * ww.x + (h1 > 0.f ? h1 : 0.f) * ww.y
                     + (h2 > 0.f ? h2 : 0.f) * ww.z + (h3 > 0.f ? h3 : 0.f) * ww.w;
            #pragma unroll
            for (int sh = 1; sh < 64; sh <<= 1) zz += __shfl_xor(zz, sh, 64);
            float val = 1.f / (1.f + expf(-(zz + b2v))) - 0.5f;
            if (l == s) {
                lsv[j]  = val;
                mabs[j] = fabsf(val);
                km[j]   = f2key(mabs[j]);
            }
        }
    }

    // ---- re-rank with exact in-band values ----
    unsigned T10b; int need10b;
    radix_topk(km, 10, T10b, need10b);
    bool mem10b[8];
    tie_member(km, T10b, need10b, mem10b);

    float zx = 0.f, cfx = -INFINITY;
    #pragma unroll
    for (int j = 0; j < 8; ++j) {
        if (mem10b[j]) zx += mabs[j];
        cfx = fmaxf(cfx, mabs[j]);
    }
    #pragma unroll
    for (int s = 1; s < 64; s <<= 1) {
        zx += __shfl_xor(zx, s, 64);
        cfx = fmaxf(cfx, __shfl_xor(cfx, s, 64));
    }
    cfx = isfinite(cfx) ? cfx : 0.f;
    float scale = (cfx >= 0.05f) ? (1.f / (zx + 1e-8f)) : 0.f;
    #pragma unroll
    for (int j = 0; j < 8; ++j) {
        int n = l + (j << 6);
        action[base + n] = mem10b[j] ? lsv[j] * scale : 0.f;
    }
    if (l == 0) conf_out[b] = cfx;
}

extern "C" void kernel_launch(void* const* d_in, const int* in_sizes, int n_in,
                              void* d_out, int out_size, void* d_ws, size_t ws_size,
                              hipStream_t stream)
{
    const float* X  = (const float*)d_in[0];
    const float* sp = (const float*)d_in[1];
    const float* vo = (const float*)d_in[2];
    const float* W1 = (const float*)d_in[3];
    const float* b1 = (const float*)d_in[4];
    const float* W2 = (const float*)d_in[5];
    const float* b2 = (const float*)d_in[6];

    float* action = (float*)d_out;
    float* conf   = action + (size_t)B_ * N_;

    float* ls = (float*)d_ws;                       // 4 MB
    size_t need = (size_t)B_ * N_ * 4 + 2 * (size_t)D_ * H_ * 2;
    short *WpH, *WpL;
    if (ws_size >= need) {
        WpH = (short*)((char*)d_ws + (size_t)B_ * N_ * 4);
        WpL = WpH + (size_t)D_ * H_;
    } else {
        WpH = (short*)(action + (size_t)out_size - 2 * (size_t)D_ * H_ / 2);
        WpL = WpH + (size_t)D_ * H_;
    }

    hipLaunchKernelGGL(pack_w, dim3(16), dim3(256), 0, stream, W1, WpH, WpL);
    hipLaunchKernelGGL(mlp_mfma, dim3(GRID_MLP), dim3(256), 0, stream,
                       X, WpH, WpL, b1, W2, b2, ls);
    hipLaunchKernelGGL(select_kernel, dim3(B_ / 4), dim3(256), 0, stream,
                       ls, sp, vo, X, W1, b1, W2, b2, action, conf);
}

// Round 13
// 299.183 us; speedup vs baseline: 1.6373x; 1.6373x over previous
//
#include <hip/hip_runtime.h>
#include <hip/hip_bf16.h>
#include <math.h>

#define B_ 2048
#define N_ 512
#define D_ 128
#define H_ 256
#define BANDf 2e-4f   // repair band: >= 2x worst-case bf16x3 score error (~1e-5..5e-5)
#define TILE_R 32

typedef __attribute__((ext_vector_type(8))) short bf16x8;
typedef __attribute__((ext_vector_type(4))) float f32x4;

__device__ __forceinline__ short f2bf(float x) {          // rne f32 -> bf16
    unsigned u = __float_as_uint(x);
    u = u + 0x7fffu + ((u >> 16) & 1u);
    return (short)(u >> 16);
}
__device__ __forceinline__ float bf2f(short h) {
    return __uint_as_float(((unsigned)(unsigned short)h) << 16);
}
__device__ __forceinline__ unsigned cvt_pk_bf16(float a, float b) { // [lo]=bf(a) [hi]=bf(b)
    unsigned r;
    asm("v_cvt_pk_bf16_f32 %0, %1, %2" : "=v"(r) : "v"(a), "v"(b));
    return r;
}
template<int K>
__device__ __forceinline__ float dpp_shr_add(float zz) {   // row_shr add within 16-lane rows
    int s = __builtin_amdgcn_update_dpp(0, __float_as_int(zz), 0x110 | K, 0xf, 0xf, true);
    return zz + __int_as_float(s);
}

// ---------------- W1 pre-pack: fragment-ordered bf16 hi/lo ----------------
// B-frag (16x16x32): lane l holds B[k = ks*32 + (l>>4)*8 + j][n = nf*16 + (l&15)]
__global__ __launch_bounds__(256) void pack_w(const float* __restrict__ W1,
                                              short* __restrict__ WpH,
                                              short* __restrict__ WpL)
{
    int tid = blockIdx.x * 256 + threadIdx.x;   // 0..4095
    int l  = tid & 63;
    int ks = (tid >> 6) & 3;
    int nf = tid >> 8;
    int n  = nf * 16 + (l & 15);
    int kb = ks * 32 + ((l >> 4) << 3);
    bf16x8 hi, lo;
    #pragma unroll
    for (int j = 0; j < 8; ++j) {
        float w = W1[(size_t)(kb + j) * H_ + n];
        short h = f2bf(w);
        hi[j] = h;
        lo[j] = f2bf(w - bf2f(h));
    }
    *(bf16x8*)&WpH[(size_t)tid * 8] = hi;
    *(bf16x8*)&WpL[(size_t)tid * 8] = lo;
}

// ---------------- MLP via bf16x3 MFMA — non-persistent, 32-row tile, 4 blocks/CU ----------------
// 32768 blocks x 256 thr (4 waves); one 32-row x 256-col tile per block.
// Wave wn owns cols wn*64..+63 (q=0..3), rows 0..31 (mf=0..1). acc 32 AGPR, B-hi 64 VGPR.
__global__ __launch_bounds__(256, 4) void mlp_mfma(
    const float* __restrict__ X, const short* __restrict__ WpH,
    const short* __restrict__ WpL, const float* __restrict__ b1,
    const float* __restrict__ W2, const float* __restrict__ b2,
    float* __restrict__ ls)
{
    __shared__ short Xh[TILE_R * 128];
    __shared__ short Xl[TILE_R * 128];
    __shared__ float zl[128];

    const int t    = threadIdx.x;
    const int lane = t & 63;
    const int wn   = t >> 6;
    const size_t m0 = (size_t)blockIdx.x * TILE_R;

    const bf16x8* WH = (const bf16x8*)WpH;
    const bf16x8* WL = (const bf16x8*)WpL;

    // resident B-hi fragments (64 VGPR); B-lo streamed from L2 per ks
    bf16x8 Bhi[4][4];
    #pragma unroll
    for (int q = 0; q < 4; ++q)
        #pragma unroll
        for (int ks = 0; ks < 4; ++ks)
            Bhi[q][ks] = WH[((wn * 4 + q) * 4 + ks) * 64 + lane];

    // stage X tile -> bf16 hi/lo via hw packed cvt, swizzled [row][k]
    {
        const float4* Xg = (const float4*)(X + m0 * D_);
        #pragma unroll
        for (int i = 0; i < 4; ++i) {
            int f = t + i * 256;
            float4 v = Xg[f];
            int row = f >> 5, k0 = (f & 31) << 2;
            unsigned h01 = cvt_pk_bf16(v.x, v.y);
            unsigned h23 = cvt_pk_bf16(v.z, v.w);
            float l0 = v.x - __uint_as_float(h01 << 16);
            float l1 = v.y - __uint_as_float(h01 & 0xffff0000u);
            float l2 = v.z - __uint_as_float(h23 << 16);
            float l3 = v.w - __uint_as_float(h23 & 0xffff0000u);
            unsigned lo01 = cvt_pk_bf16(l0, l1);
            unsigned lo23 = cvt_pk_bf16(l2, l3);
            int sidx = (row * 128 + k0) ^ ((row & 7) << 3);
            *(uint2*)&Xh[sidx] = make_uint2(h01, h23);
            *(uint2*)&Xl[sidx] = make_uint2(lo01, lo23);
        }
    }
    __syncthreads();

    f32x4 acc[2][4];
    #pragma unroll
    for (int mf = 0; mf < 2; ++mf)
        #pragma unroll
        for (int q = 0; q < 4; ++q)
            acc[mf][q] = (f32x4){0.f, 0.f, 0.f, 0.f};

    #pragma unroll
    for (int ks = 0; ks < 4; ++ks) {
        bf16x8 Blo[4];
        #pragma unroll
        for (int q = 0; q < 4; ++q)
            Blo[q] = WL[((wn * 4 + q) * 4 + ks) * 64 + lane];
        #pragma unroll
        for (int mf = 0; mf < 2; ++mf) {
            int r = mf * 16 + (lane & 15);
            int sidx = (r * 128 + ks * 32 + ((lane >> 4) << 3)) ^ ((r & 7) << 3);
            bf16x8 Ah = *(const bf16x8*)&Xh[sidx];
            bf16x8 Al = *(const bf16x8*)&Xl[sidx];
            #pragma unroll
            for (int q = 0; q < 4; ++q) {
                acc[mf][q] = __builtin_amdgcn_mfma_f32_16x16x32_bf16(Ah, Bhi[q][ks], acc[mf][q], 0, 0, 0);
                acc[mf][q] = __builtin_amdgcn_mfma_f32_16x16x32_bf16(Al, Bhi[q][ks], acc[mf][q], 0, 0, 0);
                acc[mf][q] = __builtin_amdgcn_mfma_f32_16x16x32_bf16(Ah, Blo[q],     acc[mf][q], 0, 0, 0);
            }
        }
    }

    // epilogue: h=relu(acc+b1); z=h@W2; DPP row-reduce (VALU pipe, no DS ops)
    float b1v[4], w2v[4];
    #pragma unroll
    for (int q = 0; q < 4; ++q) {
        int c = wn * 64 + q * 16 + (lane & 15);
        b1v[q] = b1[c];
        w2v[q] = W2[c];
    }
    #pragma unroll
    for (int mf = 0; mf < 2; ++mf) {
        #pragma unroll
        for (int i = 0; i < 4; ++i) {
            float zz = 0.f;
            #pragma unroll
            for (int q = 0; q < 4; ++q) {
                float h = acc[mf][q][i] + b1v[q];
                h = h > 0.f ? h : 0.f;
                zz += h * w2v[q];
            }
            zz = dpp_shr_add<1>(zz);
            zz = dpp_shr_add<2>(zz);
            zz = dpp_shr_add<4>(zz);
            zz = dpp_shr_add<8>(zz);            // lane (l&15)==15 holds row sum over wave's 64 cols
            if ((lane & 15) == 15) zl[wn * 32 + mf * 16 + ((lane >> 4) << 2) + i] = zz;
        }
    }
    __syncthreads();
    if (t < TILE_R) {
        float z = zl[t] + zl[32 + t] + zl[64 + t] + zl[96 + t] + b2[0];
        ls[m0 + t] = 1.f / (1.f + expf(-z)) - 0.5f;
    }
}

// ---------------- radix-select machinery (ballot-based, no DS ops) ----------------
__device__ __forceinline__ unsigned f2key(float f) {      // monotone float->uint
    unsigned u = __float_as_uint(f);
    return (u & 0x80000000u) ? ~u : (u | 0x80000000u);
}
__device__ __forceinline__ float key2f(unsigned k) {
    return __uint_as_float((k & 0x80000000u) ? (k & 0x7fffffffu) : ~k);
}
__device__ __forceinline__ int lane_lt_count(unsigned long long m) {
    return __builtin_amdgcn_mbcnt_hi((unsigned)(m >> 32),
           __builtin_amdgcn_mbcnt_lo((unsigned)m, 0));
}

__device__ __forceinline__ void radix_topk(const unsigned (&key)[8], int k,
                                           unsigned &T, int &need)
{
    unsigned prefix = 0, maskhi = 0;
    int kk = k;
    for (int bit = 31; bit >= 0; --bit) {
        unsigned b = 1u << bit;
        int cnt1 = 0;
        #pragma unroll
        for (int j = 0; j < 8; ++j) {
            bool one = ((key[j] & maskhi) == prefix) && (key[j] & b);
            cnt1 += __popcll(__ballot(one));
        }
        if (cnt1 >= kk) prefix |= b; else kk -= cnt1;
        maskhi |= b;
    }
    T = prefix; need = kk;
}

// membership, lowest-global-index tiebreak (slot n = l + 64*j => rank by (j, lane))
__device__ __forceinline__ void tie_member(const unsigned (&key)[8], unsigned T,
                                           int need, bool (&mem)[8])
{
    int base = 0;
    #pragma unroll
    for (int j = 0; j < 8; ++j) {
        unsigned long long eb = __ballot(key[j] == T);
        int r = base + lane_lt_count(eb);
        mem[j] = (key[j] > T) || ((key[j] == T) && (r < need));
        base += __popcll(eb);
    }
}

// ---------------- selection: 1 wave/row, barrier-free; exact band-repair ----------------
__global__ __launch_bounds__(256) void select_kernel(
    const float* __restrict__ ls, const float* __restrict__ spread,
    const float* __restrict__ vol, const float* __restrict__ X,
    const float* __restrict__ W1, const float* __restrict__ b1,
    const float* __restrict__ W2, const float* __restrict__ b2,
    float* __restrict__ action, float* __restrict__ conf_out)
{
    const int t = threadIdx.x;
    const int l = t & 63;
    const int w = t >> 6;
    const int b = blockIdx.x * 4 + w;
    const size_t base = (size_t)b * N_;

    float rv[8], lsv[8];
    unsigned kr[8];
    bool anyv = false;
    #pragma unroll
    for (int j = 0; j < 8; ++j) {
        int n = l + (j << 6);
        float sp = spread[base + n];
        float vo = vol[base + n];
        bool valid = isfinite(sp) && (sp > 0.f);
        rv[j]  = valid ? (vo / (sp + 1e-8f)) : -INFINITY;
        lsv[j] = ls[base + n];
        anyv |= valid;
        kr[j] = f2key(rv[j]);
    }
    bool allow_all = (__any((int)anyv) == 0);

    unsigned T50; int need50;
    radix_topk(kr, 50, T50, need50);
    bool mem50[8];
    tie_member(kr, T50, need50, mem50);

    float mabs[8];
    unsigned km[8];
    #pragma unroll
    for (int j = 0; j < 8; ++j) {
        bool u = allow_all || mem50[j];
        mabs[j] = u ? fabsf(lsv[j]) : -INFINITY;
        km[j] = f2key(mabs[j]);
    }
    unsigned T10; int need10;
    radix_topk(km, 10, T10, need10);
    bool mem10[8];
    tie_member(km, T10, need10, mem10);
    float b10 = key2f(T10);

    // Z, conf in one butterfly
    float zp = 0.f, cf = -INFINITY;
    #pragma unroll
    for (int j = 0; j < 8; ++j) {
        if (mem10[j]) zp += mabs[j];
        cf = fmaxf(cf, mabs[j]);
    }
    #pragma unroll
    for (int s = 1; s < 64; s <<= 1) {
        zp += __shfl_xor(zp, s, 64);
        cf = fmaxf(cf, __shfl_xor(cf, s, 64));
    }
    float conf = cf;

    // band analysis: how many universe assets within BAND of the 10th value?
    bool confclose = fabsf(conf - 0.05f) <= BANDf;
    bool inband[8];
    int nb = 0;
    #pragma unroll
    for (int j = 0; j < 8; ++j) {
        inband[j] = (mabs[j] != -INFINITY) && (fabsf(mabs[j] - b10) <= BANDf);
        nb += __popcll(__ballot(inband[j]));
    }
    bool redo = (nb >= 2) || confclose;

    if (!redo) {
        float cfin  = isfinite(conf) ? conf : 0.f;
        float scale = (cfin >= 0.05f) ? (1.f / (zp + 1e-8f)) : 0.f;
        #pragma unroll
        for (int j = 0; j < 8; ++j) {
            int n = l + (j << 6);
            action[base + n] = mem10[j] ? lsv[j] * scale : 0.f;
        }
        if (l == 0) conf_out[b] = cfin;
        return;
    }

    // ---- exact recompute of band/conf candidates (wave-cooperative) ----
    const float2* xr2 = (const float2*)&X[base * D_];   // row view: [N][64 float2]
    float4 bb = *(const float4*)&b1[l * 4];
    float4 ww = *(const float4*)&W2[l * 4];
    const float b2v = b2[0];

    #pragma unroll
    for (int j = 0; j < 8; ++j) {
        bool cand = (nb >= 2 && inband[j]) || (confclose && mabs[j] == conf);
        unsigned long long bal = __ballot(cand);
        while (bal) {
            int s = __ffsll((long long)bal) - 1;
            bal &= bal - 1;
            int asset = s + (j << 6);
            float2 x2 = xr2[(size_t)asset * 64 + l];    // lane l holds k=2l,2l+1
            float h0 = 0.f, h1 = 0.f, h2 = 0.f, h3 = 0.f;
            #pragma unroll 16
            for (int kk = 0; kk < D_; ++kk) {
                float xk = __shfl((kk & 1) ? x2.y : x2.x, kk >> 1, 64);
                float4 wv = *(const float4*)&W1[(size_t)kk * H_ + l * 4];
                h0 += xk * wv.x; h1 += xk * wv.y; h2 += xk * wv.z; h3 += xk * wv.w;
            }
            h0 += bb.x; h1 += bb.y; h2 += bb.z; h3 += bb.w;
            float zz = (h0 > 0.f ? h0 : 0.f) * ww.x + (h1 > 0.f ? h1 : 0.f) * ww.y
                     + (h2 > 0.f ? h2 : 0.f) * ww.z + (h3 > 0.f ? h3 : 0.f) * ww.w;
            #pragma unroll
            for (int sh = 1; sh < 64; sh <<= 1) zz += __shfl_xor(zz, sh, 64);
            float val = 1.f / (1.f + expf(-(zz + b2v))) - 0.5f;
            if (l == s) {
                lsv[j]  = val;
                mabs[j] = fabsf(val);
                km[j]   = f2key(mabs[j]);
            }
        }
    }

    // ---- re-rank with exact in-band values ----
    unsigned T10b; int need10b;
    radix_topk(km, 10, T10b, need10b);
    bool mem10b[8];
    tie_member(km, T10b, need10b, mem10b);

    float zx = 0.f, cfx = -INFINITY;
    #pragma unroll
    for (int j = 0; j < 8; ++j) {
        if (mem10b[j]) zx += mabs[j];
        cfx = fmaxf(cfx, mabs[j]);
    }
    #pragma unroll
    for (int s = 1; s < 64; s <<= 1) {
        zx += __shfl_xor(zx, s, 64);
        cfx = fmaxf(cfx, __shfl_xor(cfx, s, 64));
    }
    cfx = isfinite(cfx) ? cfx : 0.f;
    float scale = (cfx >= 0.05f) ? (1.f / (zx + 1e-8f)) : 0.f;
    #pragma unroll
    for (int j = 0; j < 8; ++j) {
        int n = l + (j << 6);
        action[base + n] = mem10b[j] ? lsv[j] * scale : 0.f;
    }
    if (l == 0) conf_out[b] = cfx;
}

extern "C" void kernel_launch(void* const* d_in, const int* in_sizes, int n_in,
                              void* d_out, int out_size, void* d_ws, size_t ws_size,
                              hipStream_t stream)
{
    const float* X  = (const float*)d_in[0];
    const float* sp = (const float*)d_in[1];
    const float* vo = (const float*)d_in[2];
    const float* W1 = (const float*)d_in[3];
    const float* b1 = (const float*)d_in[4];
    const float* W2 = (const float*)d_in[5];
    const float* b2 = (const float*)d_in[6];

    float* action = (float*)d_out;
    float* conf   = action + (size_t)B_ * N_;

    float* ls = (float*)d_ws;                       // 4 MB
    size_t need = (size_t)B_ * N_ * 4 + 2 * (size_t)D_ * H_ * 2;
    short *WpH, *WpL;
    if (ws_size >= need) {
        WpH = (short*)((char*)d_ws + (size_t)B_ * N_ * 4);
        WpL = WpH + (size_t)D_ * H_;
    } else {
        WpH = (short*)(action + (size_t)out_size - 2 * (size_t)D_ * H_ / 2);
        WpL = WpH + (size_t)D_ * H_;
    }

    hipLaunchKernelGGL(pack_w, dim3(16), dim3(256), 0, stream, W1, WpH, WpL);
    hipLaunchKernelGGL(mlp_mfma, dim3((B_ * N_) / TILE_R), dim3(256), 0, stream,
                       X, WpH, WpL, b1, W2, b2, ls);
    hipLaunchKernelGGL(select_kernel, dim3(B_ / 4), dim3(256), 0, stream,
                       ls, sp, vo, X, W1, b1, W2, b2, action, conf);
}

// Round 15
// 277.847 us; speedup vs baseline: 1.7630x; 1.0768x over previous
//
#include <hip/hip_runtime.h>
#include <hip/hip_bf16.h>
#include <math.h>

#define B_ 2048
#define N_ 512
#define D_ 128
#define H_ 256
#define BANDf 2e-4f   // repair band: >= 2x worst-case bf16x3 score error (~1e-5..5e-5)

typedef __attribute__((ext_vector_type(8))) short bf16x8;
typedef __attribute__((ext_vector_type(4))) float f32x4;

__device__ __forceinline__ short f2bf(float x) {          // rne f32 -> bf16
    unsigned u = __float_as_uint(x);
    u = u + 0x7fffu + ((u >> 16) & 1u);
    return (short)(u >> 16);
}
__device__ __forceinline__ float bf2f(short h) {
    return __uint_as_float(((unsigned)(unsigned short)h) << 16);
}
__device__ __forceinline__ unsigned cvt_pk_bf16(float a, float b) { // [lo]=bf(a) [hi]=bf(b)
    unsigned r;
    asm("v_cvt_pk_bf16_f32 %0, %1, %2" : "=v"(r) : "v"(a), "v"(b));
    return r;
}
template<int K>
__device__ __forceinline__ float dpp_shr_add(float zz) {   // row_shr add within 16-lane rows
    int s = __builtin_amdgcn_update_dpp(0, __float_as_int(zz), 0x110 | K, 0xf, 0xf, true);
    return zz + __int_as_float(s);
}

// ---------------- W1 pre-pack: fragment-ordered bf16 hi/lo ----------------
// B-frag (16x16x32): lane l holds B[k = ks*32 + (l>>4)*8 + j][n = nf*16 + (l&15)]
__global__ __launch_bounds__(256) void pack_w(const float* __restrict__ W1,
                                              short* __restrict__ WpH,
                                              short* __restrict__ WpL)
{
    int tid = blockIdx.x * 256 + threadIdx.x;   // 0..4095
    int l  = tid & 63;
    int ks = (tid >> 6) & 3;
    int nf = tid >> 8;
    int n  = nf * 16 + (l & 15);
    int kb = ks * 32 + ((l >> 4) << 3);
    bf16x8 hi, lo;
    #pragma unroll
    for (int j = 0; j < 8; ++j) {
        float w = W1[(size_t)(kb + j) * H_ + n];
        short h = f2bf(w);
        hi[j] = h;
        lo[j] = f2bf(w - bf2f(h));
    }
    *(bf16x8*)&WpH[(size_t)tid * 8] = hi;
    *(bf16x8*)&WpL[(size_t)tid * 8] = lo;
}

// ---------------- MLP via bf16x3 MFMA — non-persistent + Blo prefetch + setprio ----------------
// 16384 blocks x 256 thr (4 waves); one 64-row x 256-col tile per block.
// Wave wn owns cols wn*64..+63 (q=0..3). B-hi resident (64 VGPR), B-lo dbuf one ks ahead (32 VGPR).
__global__ __launch_bounds__(256, 2) void mlp_mfma(
    const float* __restrict__ X, const short* __restrict__ WpH,
    const short* __restrict__ WpL, const float* __restrict__ b1,
    const float* __restrict__ W2, const float* __restrict__ b2,
    float* __restrict__ ls)
{
    __shared__ short Xh[64 * 128];
    __shared__ short Xl[64 * 128];
    __shared__ float zl[256];

    const int t    = threadIdx.x;
    const int lane = t & 63;
    const int wn   = t >> 6;
    const size_t m0 = (size_t)blockIdx.x * 64;

    const bf16x8* WH = (const bf16x8*)WpH;
    const bf16x8* WL = (const bf16x8*)WpL;

    // resident B-hi fragments (64 VGPR) + B-lo ks=0 preload (latency hides under staging)
    bf16x8 Bhi[4][4];
    #pragma unroll
    for (int q = 0; q < 4; ++q)
        #pragma unroll
        for (int ks = 0; ks < 4; ++ks)
            Bhi[q][ks] = WH[((wn * 4 + q) * 4 + ks) * 64 + lane];

    bf16x8 Blo[2][4];
    #pragma unroll
    for (int q = 0; q < 4; ++q)
        Blo[0][q] = WL[((wn * 4 + q) * 4 + 0) * 64 + lane];

    // stage X tile -> bf16 hi/lo via hw packed cvt, swizzled [row][k]
    {
        const float4* Xg = (const float4*)(X + m0 * D_);
        #pragma unroll
        for (int i = 0; i < 8; ++i) {
            int f = t + i * 256;
            float4 v = Xg[f];
            int row = f >> 5, k0 = (f & 31) << 2;
            unsigned h01 = cvt_pk_bf16(v.x, v.y);
            unsigned h23 = cvt_pk_bf16(v.z, v.w);
            float l0 = v.x - __uint_as_float(h01 << 16);
            float l1 = v.y - __uint_as_float(h01 & 0xffff0000u);
            float l2 = v.z - __uint_as_float(h23 << 16);
            float l3 = v.w - __uint_as_float(h23 & 0xffff0000u);
            unsigned lo01 = cvt_pk_bf16(l0, l1);
            unsigned lo23 = cvt_pk_bf16(l2, l3);
            int sidx = (row * 128 + k0) ^ ((row & 7) << 3);
            *(uint2*)&Xh[sidx] = make_uint2(h01, h23);
            *(uint2*)&Xl[sidx] = make_uint2(lo01, lo23);
        }
    }
    __syncthreads();

    f32x4 acc[4][4];
    #pragma unroll
    for (int mf = 0; mf < 4; ++mf)
        #pragma unroll
        for (int q = 0; q < 4; ++q)
            acc[mf][q] = (f32x4){0.f, 0.f, 0.f, 0.f};

    __builtin_amdgcn_s_setprio(1);
    #pragma unroll
    for (int ks = 0; ks < 4; ++ks) {
        const int cur = ks & 1, nxt = cur ^ 1;
        if (ks < 3) {                            // prefetch next ks's B-lo (L2) one ks ahead
            #pragma unroll
            for (int q = 0; q < 4; ++q)
                Blo[nxt][q] = WL[((wn * 4 + q) * 4 + ks + 1) * 64 + lane];
        }
        #pragma unroll
        for (int mf = 0; mf < 4; ++mf) {
            int r = mf * 16 + (lane & 15);
            int sidx = (r * 128 + ks * 32 + ((lane >> 4) << 3)) ^ ((r & 7) << 3);
            bf16x8 Ah = *(const bf16x8*)&Xh[sidx];
            bf16x8 Al = *(const bf16x8*)&Xl[sidx];
            #pragma unroll
            for (int q = 0; q < 4; ++q) {
                acc[mf][q] = __builtin_amdgcn_mfma_f32_16x16x32_bf16(Ah, Bhi[q][ks],  acc[mf][q], 0, 0, 0);
                acc[mf][q] = __builtin_amdgcn_mfma_f32_16x16x32_bf16(Al, Bhi[q][ks],  acc[mf][q], 0, 0, 0);
                acc[mf][q] = __builtin_amdgcn_mfma_f32_16x16x32_bf16(Ah, Blo[cur][q], acc[mf][q], 0, 0, 0);
            }
        }
    }
    __builtin_amdgcn_s_setprio(0);

    // epilogue: h=relu(acc+b1); z=h@W2; DPP row-reduce (VALU pipe, no DS ops)
    float b1v[4], w2v[4];
    #pragma unroll
    for (int q = 0; q < 4; ++q) {
        int c = wn * 64 + q * 16 + (lane & 15);
        b1v[q] = b1[c];
        w2v[q] = W2[c];
    }
    #pragma unroll
    for (int mf = 0; mf < 4; ++mf) {
        #pragma unroll
        for (int i = 0; i < 4; ++i) {
            float zz = 0.f;
            #pragma unroll
            for (int q = 0; q < 4; ++q) {
                float h = acc[mf][q][i] + b1v[q];
                h = h > 0.f ? h : 0.f;
                zz += h * w2v[q];
            }
            zz = dpp_shr_add<1>(zz);
            zz = dpp_shr_add<2>(zz);
            zz = dpp_shr_add<4>(zz);
            zz = dpp_shr_add<8>(zz);            // lane (l&15)==15 holds row sum over wave's 64 cols
            if ((lane & 15) == 15) zl[wn * 64 + mf * 16 + ((lane >> 4) << 2) + i] = zz;
        }
    }
    __syncthreads();
    if (t < 64) {
        float z = zl[t] + zl[64 + t] + zl[128 + t] + zl[192 + t] + b2[0];
        ls[m0 + t] = 1.f / (1.f + expf(-z)) - 0.5f;
    }
}

// ---------------- radix-select machinery (ballot-based, no DS ops) ----------------
__device__ __forceinline__ unsigned f2key(float f) {      // monotone float->uint
    unsigned u = __float_as_uint(f);
    return (u & 0x80000000u) ? ~u : (u | 0x80000000u);
}
__device__ __forceinline__ float key2f(unsigned k) {
    return __uint_as_float((k & 0x80000000u) ? (k & 0x7fffffffu) : ~k);
}
__device__ __forceinline__ int lane_lt_count(unsigned long long m) {
    return __builtin_amdgcn_mbcnt_hi((unsigned)(m >> 32),
           __builtin_amdgcn_mbcnt_lo((unsigned)m, 0));
}

__device__ __forceinline__ void radix_topk(const unsigned (&key)[8], int k,
                                           unsigned &T, int &need)
{
    unsigned prefix = 0, maskhi = 0;
    int kk = k;
    for (int bit = 31; bit >= 0; --bit) {
        unsigned b = 1u << bit;
        int cnt1 = 0;
        #pragma unroll
        for (int j = 0; j < 8; ++j) {
            bool one = ((key[j] & maskhi) == prefix) && (key[j] & b);
            cnt1 += __popcll(__ballot(one));
        }
        if (cnt1 >= kk) prefix |= b; else kk -= cnt1;
        maskhi |= b;
    }
    T = prefix; need = kk;
}

// membership, lowest-global-index tiebreak (slot n = l + 64*j => rank by (j, lane))
__device__ __forceinline__ void tie_member(const unsigned (&key)[8], unsigned T,
                                           int need, bool (&mem)[8])
{
    int base = 0;
    #pragma unroll
    for (int j = 0; j < 8; ++j) {
        unsigned long long eb = __ballot(key[j] == T);
        int r = base + lane_lt_count(eb);
        mem[j] = (key[j] > T) || ((key[j] == T) && (r < need));
        base += __popcll(eb);
    }
}

// ---------------- selection: 1 wave/row, barrier-free; exact band-repair ----------------
__global__ __launch_bounds__(256) void select_kernel(
    const float* __restrict__ ls, const float* __restrict__ spread,
    const float* __restrict__ vol, const float* __restrict__ X,
    const float* __restrict__ W1, const float* __restrict__ b1,
    const float* __restrict__ W2, const float* __restrict__ b2,
    float* __restrict__ action, float* __restrict__ conf_out)
{
    const int t = threadIdx.x;
    const int l = t & 63;
    const int w = t >> 6;
    const int b = blockIdx.x * 4 + w;
    const size_t base = (size_t)b * N_;

    float rv[8], lsv[8];
    unsigned kr[8];
    bool anyv = false;
    #pragma unroll
    for (int j = 0; j < 8; ++j) {
        int n = l + (j << 6);
        float sp = spread[base + n];
        float vo = vol[base + n];
        bool valid = isfinite(sp) && (sp > 0.f);
        rv[j]  = valid ? (vo / (sp + 1e-8f)) : -INFINITY;
        lsv[j] = ls[base + n];
        anyv |= valid;
        kr[j] = f2key(rv[j]);
    }
    bool allow_all = (__any((int)anyv) == 0);

    unsigned T50; int need50;
    radix_topk(kr, 50, T50, need50);
    bool mem50[8];
    tie_member(kr, T50, need50, mem50);

    float mabs[8];
    unsigned km[8];
    #pragma unroll
    for (int j = 0; j < 8; ++j) {
        bool u = allow_all || mem50[j];
        mabs[j] = u ? fabsf(lsv[j]) : -INFINITY;
        km[j] = f2key(mabs[j]);
    }
    unsigned T10; int need10;
    radix_topk(km, 10, T10, need10);
    bool mem10[8];
    tie_member(km, T10, need10, mem10);
    float b10 = key2f(T10);

    // Z, conf in one butterfly
    float zp = 0.f, cf = -INFINITY;
    #pragma unroll
    for (int j = 0; j < 8; ++j) {
        if (mem10[j]) zp += mabs[j];
        cf = fmaxf(cf, mabs[j]);
    }
    #pragma unroll
    for (int s = 1; s < 64; s <<= 1) {
        zp += __shfl_xor(zp, s, 64);
        cf = fmaxf(cf, __shfl_xor(cf, s, 64));
    }
    float conf = cf;

    // band analysis: how many universe assets within BAND of the 10th value?
    bool confclose = fabsf(conf - 0.05f) <= BANDf;
    bool inband[8];
    int nb = 0;
    #pragma unroll
    for (int j = 0; j < 8; ++j) {
        inband[j] = (mabs[j] != -INFINITY) && (fabsf(mabs[j] - b10) <= BANDf);
        nb += __popcll(__ballot(inband[j]));
    }
    bool redo = (nb >= 2) || confclose;

    if (!redo) {
        float cfin  = isfinite(conf) ? conf : 0.f;
        float scale = (cfin >= 0.05f) ? (1.f / (zp + 1e-8f)) : 0.f;
        #pragma unroll
        for (int j = 0; j < 8; ++j) {
            int n = l + (j << 6);
            action[base + n] = mem10[j] ? lsv[j] * scale : 0.f;
        }
        if (l == 0) conf_out[b] = cfin;
        return;
    }

    // ---- exact recompute of band/conf candidates (wave-cooperative) ----
    const float2* xr2 = (const float2*)&X[base * D_];   // row view: [N][64 float2]
    float4 bb = *(const float4*)&b1[l * 4];
    float4 ww = *(const float4*)&W2[l * 4];
    const float b2v = b2[0];

    #pragma unroll
    for (int j = 0; j < 8; ++j) {
        bool cand = (nb >= 2 && inband[j]) || (confclose && mabs[j] == conf);
        unsigned long long bal = __ballot(cand);
        while (bal) {
            int s = __ffsll((long long)bal) - 1;
            bal &= bal - 1;
            int asset = s + (j << 6);
            float2 x2 = xr2[(size_t)asset * 64 + l];    // lane l holds k=2l,2l+1
            float h0 = 0.f, h1 = 0.f, h2 = 0.f, h3 = 0.f;
            #pragma unroll 16
            for (int kk = 0; kk < D_; ++kk) {
                float xk = __shfl((kk & 1) ? x2.y : x2.x, kk >> 1, 64);
                float4 wv = *(const float4*)&W1[(size_t)kk * H_ + l * 4];
                h0 += xk * wv.x; h1 += xk * wv.y; h2 += xk * wv.z; h3 += xk * wv.w;
            }
            h0 += bb.x; h1 += bb.y; h2 += bb.z; h3 += bb.w;
            float zz = (h0 > 0.f ? h0 : 0.f) * ww.x + (h1 > 0.f ? h1 : 0.f) * ww.y
                     + (h2 > 0.f ? h2 : 0.f) * ww.z + (h3 > 0.f ? h3 : 0.f) * ww.w;
            #pragma unroll
            for (int sh = 1; sh < 64; sh <<= 1) zz += __shfl_xor(zz, sh, 64);
            float val = 1.f / (1.f + expf(-(zz + b2v))) - 0.5f;
            if (l == s) {
                lsv[j]  = val;
                mabs[j] = fabsf(val);
                km[j]   = f2key(mabs[j]);
            }
        }
    }

    // ---- re-rank with exact in-band values ----
    unsigned T10b; int need10b;
    radix_topk(km, 10, T10b, need10b);
    bool mem10b[8];
    tie_member(km, T10b, need10b, mem10b);

    float zx = 0.f, cfx = -INFINITY;
    #pragma unroll
    for (int j = 0; j < 8; ++j) {
        if (mem10b[j]) zx += mabs[j];
        cfx = fmaxf(cfx, mabs[j]);
    }
    #pragma unroll
    for (int s = 1; s < 64; s <<= 1) {
        zx += __shfl_xor(zx, s, 64);
        cfx = fmaxf(cfx, __shfl_xor(cfx, s, 64));
    }
    cfx = isfinite(cfx) ? cfx : 0.f;
    float scale = (cfx >= 0.05f) ? (1.f / (zx + 1e-8f)) : 0.f;
    #pragma unroll
    for (int j = 0; j < 8; ++j) {
        int n = l + (j << 6);
        action[base + n] = mem10b[j] ? lsv[j] * scale : 0.f;
    }
    if (l == 0) conf_out[b] = cfx;
}

extern "C" void kernel_launch(void* const* d_in, const int* in_sizes, int n_in,
                              void* d_out, int out_size, void* d_ws, size_t ws_size,
                              hipStream_t stream)
{
    const float* X  = (const float*)d_in[0];
    const float* sp = (const float*)d_in[1];
    const float* vo = (const float*)d_in[2];
    const float* W1 = (const float*)d_in[3];
    const float* b1 = (const float*)d_in[4];
    const float* W2 = (const float*)d_in[5];
    const float* b2 = (const float*)d_in[6];

    float* action = (float*)d_out;
    float* conf   = action + (size_t)B_ * N_;

    float* ls = (float*)d_ws;                       // 4 MB
    size_t need = (size_t)B_ * N_ * 4 + 2 * (size_t)D_ * H_ * 2;
    short *WpH, *WpL;
    if (ws_size >= need) {
        WpH = (short*)((char*)d_ws + (size_t)B_ * N_ * 4);
        WpL = WpH + (size_t)D_ * H_;
    } else {
        WpH = (short*)(action + (size_t)out_size - 2 * (size_t)D_ * H_ / 2);
        WpL = WpH + (size_t)D_ * H_;
    }

    hipLaunchKernelGGL(pack_w, dim3(16), dim3(256), 0, stream, W1, WpH, WpL);
    hipLaunchKernelGGL(mlp_mfma, dim3((B_ * N_) / 64), dim3(256), 0, stream,
                       X, WpH, WpL, b1, W2, b2, ls);
    hipLaunchKernelGGL(select_kernel, dim3(B_ / 4), dim3(256), 0, stream,
                       ls, sp, vo, X, W1, b1, W2, b2, action, conf);
}